// Round 1
// baseline (232.590 us; speedup 1.0000x reference)
//
#include <hip/hip_runtime.h>

#define T_STEPS 512
#define BATCH   512
#define IN_DIM  128
#define GDIM    32   // 4 gates x 8 qubits

// ---------------------------------------------------------------------------
// Kernel 1: X[row][g] = sum_k inp[row][k] * W_gate[k][q]  + b_gate[q] + theta_gate[q]
// row in [0, T*B), g = gate*8 + q. Biases+theta folded in (qlayer arg = z+theta).
// 128 rows per block, 128 threads. Inputs staged in LDS with pad 129:
// compute-read banks = (lane + k) % 32 -> 2-way aliasing (free).
// W read with wave-uniform indices -> scalar loads (SMEM path, off the LDS pipe).
// Thread = (row pair rl, rl+64) x (16 outputs = 2 gates), 32 fp32 accumulators.
// ---------------------------------------------------------------------------
__global__ __launch_bounds__(128) void qlstm_xproj(
    const float* __restrict__ inp,
    const float* __restrict__ Wf, const float* __restrict__ bf,
    const float* __restrict__ Wi, const float* __restrict__ bi,
    const float* __restrict__ Wu, const float* __restrict__ bu,
    const float* __restrict__ Wo, const float* __restrict__ bo,
    const float* __restrict__ thf, const float* __restrict__ thi,
    const float* __restrict__ thu, const float* __restrict__ tho,
    float* __restrict__ X)
{
    __shared__ float tile[128 * 129];
    const int tid = threadIdx.x;
    const long long row0 = (long long)blockIdx.x * 128;

    // stage 128 rows x 128 cols, coalesced float4
    const float4* src = (const float4*)(inp + row0 * IN_DIM);
    #pragma unroll 4
    for (int i = 0; i < 32; ++i) {
        int f = tid + i * 128;
        float4 v = src[f];
        int r = f >> 5, c = (f & 31) << 2;
        float* d = &tile[r * 129 + c];
        d[0] = v.x; d[1] = v.y; d[2] = v.z; d[3] = v.w;
    }
    __syncthreads();

    const int h  = __builtin_amdgcn_readfirstlane(tid >> 6);  // wave-uniform: 0 or 1
    const int rl = tid & 63;

    const float* W0 = h ? Wu : Wf;
    const float* W1 = h ? Wo : Wi;
    const float* B0 = h ? bu : bf;
    const float* B1 = h ? bo : bi;
    const float* T0 = h ? thu : thf;
    const float* T1 = h ? tho : thi;

    float acc0[16], acc1[16];
    #pragma unroll
    for (int j = 0; j < 8; ++j) {
        float i0 = B0[j] + T0[j];
        float i1 = B1[j] + T1[j];
        acc0[j] = i0; acc0[8 + j] = i1;
        acc1[j] = i0; acc1[8 + j] = i1;
    }

    #pragma unroll 8
    for (int k = 0; k < IN_DIM; ++k) {
        float v0 = tile[rl * 129 + k];
        float v1 = tile[(rl + 64) * 129 + k];
        #pragma unroll
        for (int j = 0; j < 8; ++j) {
            float w0 = W0[k * 8 + j];   // uniform -> s_load
            float w1 = W1[k * 8 + j];
            acc0[j]     = fmaf(v0, w0, acc0[j]);
            acc0[8 + j] = fmaf(v0, w1, acc0[8 + j]);
            acc1[j]     = fmaf(v1, w0, acc1[j]);
            acc1[8 + j] = fmaf(v1, w1, acc1[8 + j]);
        }
    }

    float* X0 = X + (row0 + rl) * GDIM + h * 16;
    float* X1 = X + (row0 + rl + 64) * GDIM + h * 16;
    #pragma unroll
    for (int j = 0; j < 16; ++j) { X0[j] = acc0[j]; X1[j] = acc1[j]; }
}

// ---------------------------------------------------------------------------
// Kernel 2: the serial recurrence. One 32-lane group per batch element,
// lane = gate*8 + q; 2 batch elements per 64-lane wave; 256 blocks (1/CU).
// qlayer(z)_0 = c1*...*c7 ; qlayer(z)_j = c0*...*cj  with c_w = cos(z_w).
// tanh(x) = 2*sigmoid(2x) - 1 unifies gate activations branchlessly.
// State hx/cx replicated: lane l holds hidden unit (l & 7).
// ---------------------------------------------------------------------------
__global__ __launch_bounds__(64) void qlstm_rec(
    const float* __restrict__ X,
    const float* __restrict__ Wf, const float* __restrict__ Wi,
    const float* __restrict__ Wu, const float* __restrict__ Wo,
    float* __restrict__ out)
{
    const int tid  = threadIdx.x;
    const int sub  = tid >> 5;
    const int b    = blockIdx.x * 2 + sub;
    const int l    = tid & 31;
    const int gate = l >> 3;
    const int q    = l & 7;

    const float* Wg = (gate == 0) ? Wf : (gate == 1) ? Wi : (gate == 2) ? Wu : Wo;
    float wh[8];
    #pragma unroll
    for (int k = 0; k < 8; ++k) wh[k] = Wg[(IN_DIM + k) * 8 + q];

    const bool isTanh = (gate == 2);

    float hx = 0.f, cx = 0.f;
    float xv = X[(long long)b * GDIM + l];

    for (int t = 0; t < T_STEPS; ++t) {
        // prefetch next step's projection (hides L2/L3 latency under the chain)
        int tn = (t + 1 < T_STEPS) ? t + 1 : t;
        float xnext = X[((long long)tn * BATCH + b) * GDIM + l];

        // z = xv + hx . Wh   (tree-reassociated, broadcasts issue in parallel)
        float p0 = __shfl(hx, 0, 32) * wh[0] + __shfl(hx, 1, 32) * wh[1];
        float p1 = __shfl(hx, 2, 32) * wh[2] + __shfl(hx, 3, 32) * wh[3];
        float p2 = __shfl(hx, 4, 32) * wh[4] + __shfl(hx, 5, 32) * wh[5];
        float p3 = __shfl(hx, 6, 32) * wh[6] + __shfl(hx, 7, 32) * wh[7];
        float z = xv + ((p0 + p1) + (p2 + p3));

        float c = __cosf(z);

        // broadcast all 8 cosines within the gate's 8-lane group, masked product
        float t0, t1, t2, t3, t4, t5, t6, t7;
        {
            float c0 = __shfl(c, 0, 8), c1 = __shfl(c, 1, 8);
            float c2 = __shfl(c, 2, 8), c3 = __shfl(c, 3, 8);
            float c4 = __shfl(c, 4, 8), c5 = __shfl(c, 5, 8);
            float c6 = __shfl(c, 6, 8), c7 = __shfl(c, 7, 8);
            // mask: q==0 -> {1..7};  q>=1 -> {0..q}
            t0 = (q != 0)            ? c0 : 1.f;
            t1 = (q == 0 || q >= 1)  ? c1 : 1.f;
            t2 = (q == 0 || q >= 2)  ? c2 : 1.f;
            t3 = (q == 0 || q >= 3)  ? c3 : 1.f;
            t4 = (q == 0 || q >= 4)  ? c4 : 1.f;
            t5 = (q == 0 || q >= 5)  ? c5 : 1.f;
            t6 = (q == 0 || q >= 6)  ? c6 : 1.f;
            t7 = (q == 0 || q >= 7)  ? c7 : 1.f;
        }
        float outv = ((t0 * t1) * (t2 * t3)) * ((t4 * t5) * (t6 * t7));

        // activation: sigmoid for f,i,o ; tanh for u  (tanh = 2*sig(2x)-1)
        float a = isTanh ? 2.f * outv : outv;
        float s = __fdividef(1.f, 1.f + __expf(-a));
        float act = isTanh ? 2.f * s - 1.f : s;

        // gather the four gate values for hidden unit j = q (replicated on all lanes)
        float fv = __shfl(act, q,      32);
        float iv = __shfl(act, 8 + q,  32);
        float uv = __shfl(act, 16 + q, 32);
        float ov = __shfl(act, 24 + q, 32);

        float ncx = fmaf(fv, cx, iv * uv);
        float th  = __fdividef(1.f, 1.f + __expf(-2.f * ncx));  // sigmoid(2*ncx)
        float nhx = ov * (2.f * th - 1.f);
        cx = ncx;
        hx = nhx;

        if (l < 8) out[((long long)t * BATCH + b) * 8 + q] = nhx;
        xv = xnext;
    }

    if (l < 8) {
        out[(long long)T_STEPS * BATCH * 8 + (long long)b * 8 + q]             = hx;
        out[(long long)T_STEPS * BATCH * 8 + (long long)(BATCH + b) * 8 + q]   = cx;
    }
}

// ---------------------------------------------------------------------------
extern "C" void kernel_launch(void* const* d_in, const int* in_sizes, int n_in,
                              void* d_out, int out_size, void* d_ws, size_t ws_size,
                              hipStream_t stream) {
    const float* inp = (const float*)d_in[0];
    const float* Wf  = (const float*)d_in[1];
    const float* bf  = (const float*)d_in[2];
    const float* Wi  = (const float*)d_in[3];
    const float* bi  = (const float*)d_in[4];
    const float* Wu  = (const float*)d_in[5];
    const float* bu  = (const float*)d_in[6];
    const float* Wo  = (const float*)d_in[7];
    const float* bo  = (const float*)d_in[8];
    const float* thf = (const float*)d_in[9];
    const float* thi = (const float*)d_in[10];
    const float* thu = (const float*)d_in[11];
    const float* tho = (const float*)d_in[12];

    float* X   = (float*)d_ws;              // (T*B, 32) fp32 = 33.5 MB
    float* out = (float*)d_out;

    qlstm_xproj<<<(T_STEPS * BATCH) / 128, 128, 0, stream>>>(
        inp, Wf, bf, Wi, bi, Wu, bu, Wo, bo, thf, thi, thu, tho, X);

    qlstm_rec<<<BATCH / 2, 64, 0, stream>>>(X, Wf, Wi, Wu, Wo, out);
}

// Round 2
// 191.576 us; speedup vs baseline: 1.2141x; 1.2141x over previous
//
#include <hip/hip_runtime.h>

#define T_STEPS 512
#define BATCH   512
#define IN_DIM  128
#define GDIM    32   // 4 gates x 8 qubits

// ---------------------------------------------------------------------------
// DPP helper: compile-time control, full row/bank masks, bound_ctrl=0 (->0).
// quad_perm bcast j: ctrl = j*0x55 ; row_shr:n = 0x110|n ; row_ror:8 = 0x128 ;
// row_half_mirror = 0x141.
// ---------------------------------------------------------------------------
template <int CTRL>
__device__ __forceinline__ float dppm(float x) {
    return __int_as_float(__builtin_amdgcn_mov_dpp(__float_as_int(x), CTRL, 0xF, 0xF, true));
}

// ---------------------------------------------------------------------------
// Kernel 1: X[row][g] = inp[row] . W_gate[:,q] + b_gate[q] + theta_gate[q]
// 64 rows/block, 128 threads (2 waves), 33KB LDS -> 4 blocks/CU = 2 waves/SIMD.
// W read wave-uniformly -> s_load (constant cache, off the LDS pipe).
// ---------------------------------------------------------------------------
__global__ __launch_bounds__(128) void qlstm_xproj(
    const float* __restrict__ inp,
    const float* __restrict__ Wf, const float* __restrict__ bf,
    const float* __restrict__ Wi, const float* __restrict__ bi,
    const float* __restrict__ Wu, const float* __restrict__ bu,
    const float* __restrict__ Wo, const float* __restrict__ bo,
    const float* __restrict__ thf, const float* __restrict__ thi,
    const float* __restrict__ thu, const float* __restrict__ tho,
    float* __restrict__ X)
{
    __shared__ float tile[64 * 129];
    const int tid = threadIdx.x;
    const long long row0 = (long long)blockIdx.x * 64;

    // stage 64 rows x 128 cols, coalesced float4 (32KB contiguous per block)
    const float4* src = (const float4*)(inp + row0 * IN_DIM);
    #pragma unroll
    for (int i = 0; i < 16; ++i) {
        int f = tid + i * 128;            // 0..2047
        float4 v = src[f];
        int r = f >> 5, c = (f & 31) << 2;
        float* d = &tile[r * 129 + c];
        d[0] = v.x; d[1] = v.y; d[2] = v.z; d[3] = v.w;
    }
    __syncthreads();

    const int h  = __builtin_amdgcn_readfirstlane(tid >> 6);  // wave-uniform 0/1
    const int rl = tid & 63;                                  // row within tile

    const float* W0 = h ? Wu : Wf;
    const float* W1 = h ? Wo : Wi;
    const float* B0 = h ? bu : bf;
    const float* B1 = h ? bo : bi;
    const float* T0 = h ? thu : thf;
    const float* T1 = h ? tho : thi;

    float acc[16];
    #pragma unroll
    for (int j = 0; j < 8; ++j) {
        acc[j]     = B0[j] + T0[j];
        acc[8 + j] = B1[j] + T1[j];
    }

    #pragma unroll 8
    for (int k = 0; k < IN_DIM; ++k) {
        float v = tile[rl * 129 + k];     // banks (rl+k)%32 : 2-way = free
        #pragma unroll
        for (int j = 0; j < 8; ++j) {
            acc[j]     = fmaf(v, W0[k * 8 + j], acc[j]);   // uniform -> s_load
            acc[8 + j] = fmaf(v, W1[k * 8 + j], acc[8 + j]);
        }
    }

    float4* Xo = (float4*)(X + (row0 + rl) * GDIM + h * 16);
    Xo[0] = make_float4(acc[0],  acc[1],  acc[2],  acc[3]);
    Xo[1] = make_float4(acc[4],  acc[5],  acc[6],  acc[7]);
    Xo[2] = make_float4(acc[8],  acc[9],  acc[10], acc[11]);
    Xo[3] = make_float4(acc[12], acc[13], acc[14], acc[15]);
}

// ---------------------------------------------------------------------------
// Kernel 2: serial recurrence, zero LDS traffic — all cross-lane via DPP.
// 16 lanes per batch (4 batches/wave, 128 blocks x 1 wave).
// lane l in 16-group: q = l&7 ; A-stream gate = l>>3 (0=f,1=i, sigmoid),
// B-stream gate = 2+(l>>3) (2=u tanh, 3=o sigmoid). hx/cx replicated (unit q).
// qlayer: out_j = prod cos(z_w) over mask; masks are prefixes ->
//   3-step DPP row_shr scan; lane0 (mask {1..7}) = fullprod * rcp(c0).
// ---------------------------------------------------------------------------
__global__ __launch_bounds__(64) void qlstm_rec(
    const float* __restrict__ X,
    const float* __restrict__ Wf, const float* __restrict__ Wi,
    const float* __restrict__ Wu, const float* __restrict__ Wo,
    float* __restrict__ out)
{
    const int lane = threadIdx.x;
    const int g16  = lane >> 4;
    const int l    = lane & 15;
    const int q    = lane & 7;
    const int gA   = (lane >> 3) & 1;
    const int b    = blockIdx.x * 4 + g16;

    const bool ql   = ((lane >> 2) & 1) == 0;  // low quad of 8-group
    const bool lo8  = (l < 8);
    const bool ge1  = (q >= 1), ge2 = (q >= 2), ge4 = (q >= 4);
    const bool isq0 = (q == 0);

    const float* WA = gA ? Wi : Wf;
    const float* WB = gA ? Wo : Wu;
    float wA[8], wB[8];
    #pragma unroll
    for (int k = 0; k < 8; ++k) {
        wA[k] = WA[(IN_DIM + k) * 8 + q];
        wB[k] = WB[(IN_DIM + k) * 8 + q];
    }

    const float L2E = 1.442695040888963f;
    const float m1A = -L2E;                         // A: always sigmoid
    const float m1B = lo8 ? -2.0f * L2E : -L2E;     // B: u=tanh, o=sigmoid
    const float scB = lo8 ? 2.0f : 1.0f;
    const float biB = lo8 ? -1.0f : 0.0f;

    float hx = 0.0f, cx = 0.0f;

    const float* X0 = X + (long long)b * GDIM;
    float xvA = X0[l],                xvB = X0[16 + l];
    const float* X1 = X + ((long long)BATCH + b) * GDIM;
    float n1A = X1[l],                n1B = X1[16 + l];

    #pragma unroll 2
    for (int t = 0; t < T_STEPS; ++t) {
        // depth-2 prefetch (covers L3 latency; X misses per-XCD L2)
        int t2 = (t + 2 < T_STEPS) ? t + 2 : T_STEPS - 1;
        const float* Xn = X + ((long long)t2 * BATCH + b) * GDIM;
        float n2A = Xn[l], n2B = Xn[16 + l];

        // ---- R1: broadcast hx[0..7] within 8-group (shared DPP pairs) ----
        float a0 = dppm<0x00>(hx), b0 = dppm<0x141>(a0);
        float a1 = dppm<0x55>(hx), b1 = dppm<0x141>(a1);
        float a2 = dppm<0xAA>(hx), b2 = dppm<0x141>(a2);
        float a3 = dppm<0xFF>(hx), b3 = dppm<0x141>(a3);
        float h0 = ql ? a0 : b0, h4 = ql ? b0 : a0;
        float h1 = ql ? a1 : b1, h5 = ql ? b1 : a1;
        float h2 = ql ? a2 : b2, h6 = ql ? b2 : a2;
        float h3 = ql ? a3 : b3, h7 = ql ? b3 : a3;

        float zA = xvA + (((h0 * wA[0] + h1 * wA[1]) + (h2 * wA[2] + h3 * wA[3]))
                        + ((h4 * wA[4] + h5 * wA[5]) + (h6 * wA[6] + h7 * wA[7])));
        float zB = xvB + (((h0 * wB[0] + h1 * wB[1]) + (h2 * wB[2] + h3 * wB[3]))
                        + ((h4 * wB[4] + h5 * wB[5]) + (h6 * wB[6] + h7 * wB[7])));

        float cA = __cosf(zA);
        float cB = __cosf(zB);

        // ---- R2: masked DPP prefix-product scan within 8-group ----
        float PA = cA, PB = cB, tt;
        tt = dppm<0x111>(PA); PA *= (ge1 ? tt : 1.0f);
        tt = dppm<0x111>(PB); PB *= (ge1 ? tt : 1.0f);
        tt = dppm<0x112>(PA); PA *= (ge2 ? tt : 1.0f);
        tt = dppm<0x112>(PB); PB *= (ge2 ? tt : 1.0f);
        tt = dppm<0x114>(PA); PA *= (ge4 ? tt : 1.0f);
        tt = dppm<0x114>(PB); PB *= (ge4 ? tt : 1.0f);
        // lane0 fixup: out0 = (c0*...*c7) * rcp(c0)  (clamped vs exact 0)
        float fullA = dppm<0x141>(PA);
        float fullB = dppm<0x141>(PB);
        float cAc = fabsf(cA) < 1e-30f ? 1e-30f : cA;
        float cBc = fabsf(cB) < 1e-30f ? 1e-30f : cB;
        float outA = isq0 ? fullA * __builtin_amdgcn_rcpf(cAc) : PA;
        float outB = isq0 ? fullB * __builtin_amdgcn_rcpf(cBc) : PB;

        // ---- activations: sigma(x)=rcp(1+exp2(-x*log2e)); tanh=2*sig(2x)-1
        float eA = __builtin_amdgcn_exp2f(outA * m1A);
        float actA = __builtin_amdgcn_rcpf(1.0f + eA);          // f or i
        float eB = __builtin_amdgcn_exp2f(outB * m1B);
        float actB = fmaf(__builtin_amdgcn_rcpf(1.0f + eB), scB, biB);  // u or o

        // ---- R3: gather f,i,u,o for unit q — one row_ror:8 per stream ----
        float rA = dppm<0x128>(actA);
        float rB = dppm<0x128>(actB);
        float fv = lo8 ? actA : rA;
        float iv = lo8 ? rA : actA;
        float uv = lo8 ? actB : rB;
        float ov = lo8 ? rB : actB;

        // ---- state update ----
        float ncx = fmaf(fv, cx, iv * uv);
        float e2  = __builtin_amdgcn_exp2f(ncx * (-2.0f * L2E));
        float th  = fmaf(__builtin_amdgcn_rcpf(1.0f + e2), 2.0f, -1.0f);
        float nhx = ov * th;
        cx = ncx;
        hx = nhx;

        if (lo8) out[((long long)t * BATCH + b) * 8 + q] = nhx;

        xvA = n1A; xvB = n1B;
        n1A = n2A; n1B = n2B;
    }

    if (lo8) {
        out[(long long)T_STEPS * BATCH * 8 + (long long)b * 8 + q]           = hx;
        out[(long long)T_STEPS * BATCH * 8 + (long long)(BATCH + b) * 8 + q] = cx;
    }
}

// ---------------------------------------------------------------------------
extern "C" void kernel_launch(void* const* d_in, const int* in_sizes, int n_in,
                              void* d_out, int out_size, void* d_ws, size_t ws_size,
                              hipStream_t stream) {
    const float* inp = (const float*)d_in[0];
    const float* Wf  = (const float*)d_in[1];
    const float* bf  = (const float*)d_in[2];
    const float* Wi  = (const float*)d_in[3];
    const float* bi  = (const float*)d_in[4];
    const float* Wu  = (const float*)d_in[5];
    const float* bu  = (const float*)d_in[6];
    const float* Wo  = (const float*)d_in[7];
    const float* bo  = (const float*)d_in[8];
    const float* thf = (const float*)d_in[9];
    const float* thi = (const float*)d_in[10];
    const float* thu = (const float*)d_in[11];
    const float* tho = (const float*)d_in[12];

    float* X   = (float*)d_ws;              // (T*B, 32) fp32 = 33.5 MB
    float* out = (float*)d_out;

    qlstm_xproj<<<(T_STEPS * BATCH) / 64, 128, 0, stream>>>(
        inp, Wf, bf, Wi, bi, Wu, bu, Wo, bo, thf, thi, thu, tho, X);

    qlstm_rec<<<BATCH / 4, 64, 0, stream>>>(X, Wf, Wi, Wu, Wo, out);
}

// Round 3
// 178.743 us; speedup vs baseline: 1.3012x; 1.0718x over previous
//
#include <hip/hip_runtime.h>

#define T_STEPS 512
#define BATCH   512
#define IN_DIM  128
#define GDIM    32   // 4 gates x 8 qubits
#define PF_D    8    // prefetch depth (steps of X ahead in registers)

typedef float f4 __attribute__((ext_vector_type(4)));

// ---------------------------------------------------------------------------
// DPP helper: quad_perm bcast j: ctrl=j*0x55 ; row_shr:n = 0x110|n ;
// row_ror:8 = 0x128 ; row_half_mirror = 0x141 (mirror within 8-lane half-row).
// ---------------------------------------------------------------------------
template <int CTRL>
__device__ __forceinline__ float dppm(float x) {
    return __int_as_float(__builtin_amdgcn_mov_dpp(__float_as_int(x), CTRL, 0xF, 0xF, true));
}

// tanh Pade[5/4]: x(945+105u+u^2)/(945+420u+15u^2), u=x^2.
// err <= ~5e-5 on [-2.2,2.2], ~1e-7 on [-1,1]. One rcp, rest FMA.
__device__ __forceinline__ float tanh_pade(float x) {
    float u = x * x;
    float n = fmaf(u, u + 105.0f, 945.0f);
    float d = fmaf(u, fmaf(u, 15.0f, 420.0f), 945.0f);
    return (x * n) * __builtin_amdgcn_rcpf(d);
}

// ---------------------------------------------------------------------------
// Kernel 1: X[row][g] = inp[row] . W_gate[:,q] + b_gate[q] + theta_gate[q]
// 64 rows/block, 128 threads (2 waves). Input loads nontemporal (streamed once,
// 134MB) so X (33.5MB) stays resident in L3 for the recurrence kernel.
// ---------------------------------------------------------------------------
__global__ __launch_bounds__(128) void qlstm_xproj(
    const float* __restrict__ inp,
    const float* __restrict__ Wf, const float* __restrict__ bf,
    const float* __restrict__ Wi, const float* __restrict__ bi,
    const float* __restrict__ Wu, const float* __restrict__ bu,
    const float* __restrict__ Wo, const float* __restrict__ bo,
    const float* __restrict__ thf, const float* __restrict__ thi,
    const float* __restrict__ thu, const float* __restrict__ tho,
    float* __restrict__ X)
{
    __shared__ float tile[64 * 129];
    const int tid = threadIdx.x;
    const long long row0 = (long long)blockIdx.x * 64;

    const f4* src = (const f4*)(inp + row0 * IN_DIM);
    #pragma unroll
    for (int i = 0; i < 16; ++i) {
        int f = tid + i * 128;            // 0..2047
        f4 v = __builtin_nontemporal_load(src + f);
        int r = f >> 5, c = (f & 31) << 2;
        float* d = &tile[r * 129 + c];
        d[0] = v.x; d[1] = v.y; d[2] = v.z; d[3] = v.w;
    }
    __syncthreads();

    const int h  = __builtin_amdgcn_readfirstlane(tid >> 6);  // wave-uniform 0/1
    const int rl = tid & 63;

    const float* W0 = h ? Wu : Wf;
    const float* W1 = h ? Wo : Wi;
    const float* B0 = h ? bu : bf;
    const float* B1 = h ? bo : bi;
    const float* T0 = h ? thu : thf;
    const float* T1 = h ? tho : thi;

    float acc[16];
    #pragma unroll
    for (int j = 0; j < 8; ++j) {
        acc[j]     = B0[j] + T0[j];
        acc[8 + j] = B1[j] + T1[j];
    }

    #pragma unroll 8
    for (int k = 0; k < IN_DIM; ++k) {
        float v = tile[rl * 129 + k];     // banks (rl+k)%32 : 2-way = free
        #pragma unroll
        for (int j = 0; j < 8; ++j) {
            acc[j]     = fmaf(v, W0[k * 8 + j], acc[j]);   // uniform -> s_load
            acc[8 + j] = fmaf(v, W1[k * 8 + j], acc[8 + j]);
        }
    }

    float4* Xo = (float4*)(X + (row0 + rl) * GDIM + h * 16);
    Xo[0] = make_float4(acc[0],  acc[1],  acc[2],  acc[3]);
    Xo[1] = make_float4(acc[4],  acc[5],  acc[6],  acc[7]);
    Xo[2] = make_float4(acc[8],  acc[9],  acc[10], acc[11]);
    Xo[3] = make_float4(acc[12], acc[13], acc[14], acc[15]);
}

// ---------------------------------------------------------------------------
// Kernel 2: serial recurrence. 16 lanes/batch, all cross-lane via DPP.
// Chain shortened: 2 serial trans ops/step (cos, act rcp); depth-8 register
// prefetch queue hides X load latency (load->use = 8 steps ~ >1400 cy).
// Activations: shared tanh Pade[5/4]; sigma(x)=0.5+0.5*tanh(x/2).
// Bounds: |qlayer out| <= 1 (product of cos), |cx| <= 2.071 (contraction).
// ---------------------------------------------------------------------------
__global__ __launch_bounds__(64) void qlstm_rec(
    const float* __restrict__ X,
    const float* __restrict__ Wf, const float* __restrict__ Wi,
    const float* __restrict__ Wu, const float* __restrict__ Wo,
    float* __restrict__ out)
{
    const int lane = threadIdx.x;
    const int g16  = lane >> 4;
    const int l    = lane & 15;
    const int q    = lane & 7;
    const int gA   = (lane >> 3) & 1;
    const int b    = blockIdx.x * 4 + g16;

    const bool ql   = ((lane >> 2) & 1) == 0;  // low quad of 8-group
    const bool lo8  = (l < 8);
    const bool ge1  = (q >= 1), ge2 = (q >= 2), ge4 = (q >= 4);
    const bool isq0 = (q == 0);

    const float* WA = gA ? Wi : Wf;
    const float* WB = gA ? Wo : Wu;
    float wA[8], wB[8];
    #pragma unroll
    for (int k = 0; k < 8; ++k) {
        wA[k] = WA[(IN_DIM + k) * 8 + q];
        wB[k] = WB[(IN_DIM + k) * 8 + q];
    }

    // B-stream activation fold: lo8 = u-gate (tanh), hi8 = o-gate (sigmoid)
    const float sB = lo8 ? 1.0f : 0.5f;   // pre-scale
    const float aB = lo8 ? 1.0f : 0.5f;   // post-scale
    const float bB = lo8 ? 0.0f : 0.5f;   // post-bias

    float hx = 0.0f, cx = 0.0f;

    const int S = BATCH * GDIM;               // 16384 elements per time slice
    const float* bp = X + b * GDIM;

    // depth-8 rolling prefetch queue
    float qAv[PF_D], qBv[PF_D];
    #pragma unroll
    for (int d = 0; d < PF_D; ++d) {
        qAv[d] = bp[d * S + l];
        qBv[d] = bp[d * S + 16 + l];
    }

    float* outp = out + b * 8 + q;            // + t*BATCH*8 per step

    for (int tt = 0; tt < T_STEPS; tt += PF_D) {
        #pragma unroll
        for (int r = 0; r < PF_D; ++r) {
            const int t = tt + r;
            float xvA = qAv[r], xvB = qBv[r];
            int tp = t + PF_D; if (tp > T_STEPS - 1) tp = T_STEPS - 1;
            qAv[r] = bp[tp * S + l];          // refill: used 8 steps later
            qBv[r] = bp[tp * S + 16 + l];

            // ---- R1: broadcast hx[0..7] within 8-group ----
            float a0 = dppm<0x00>(hx), b0 = dppm<0x141>(a0);
            float a1 = dppm<0x55>(hx), b1 = dppm<0x141>(a1);
            float a2 = dppm<0xAA>(hx), b2 = dppm<0x141>(a2);
            float a3 = dppm<0xFF>(hx), b3 = dppm<0x141>(a3);
            float h0 = ql ? a0 : b0, h4 = ql ? b0 : a0;
            float h1 = ql ? a1 : b1, h5 = ql ? b1 : a1;
            float h2 = ql ? a2 : b2, h6 = ql ? b2 : a2;
            float h3 = ql ? a3 : b3, h7 = ql ? b3 : a3;

            float zA = xvA + (((h0 * wA[0] + h1 * wA[1]) + (h2 * wA[2] + h3 * wA[3]))
                            + ((h4 * wA[4] + h5 * wA[5]) + (h6 * wA[6] + h7 * wA[7])));
            float zB = xvB + (((h0 * wB[0] + h1 * wB[1]) + (h2 * wB[2] + h3 * wB[3]))
                            + ((h4 * wB[4] + h5 * wB[5]) + (h6 * wB[6] + h7 * wB[7])));

            float cA = __cosf(zA);
            float cB = __cosf(zB);

            // ---- R2: masked DPP prefix-product scan within 8-group ----
            float PA = cA, PB = cB, tv;
            tv = dppm<0x111>(PA); PA *= (ge1 ? tv : 1.0f);
            tv = dppm<0x111>(PB); PB *= (ge1 ? tv : 1.0f);
            tv = dppm<0x112>(PA); PA *= (ge2 ? tv : 1.0f);
            tv = dppm<0x112>(PB); PB *= (ge2 ? tv : 1.0f);
            tv = dppm<0x114>(PA); PA *= (ge4 ? tv : 1.0f);
            tv = dppm<0x114>(PB); PB *= (ge4 ? tv : 1.0f);
            // lane0: out0 = (c0..c7) * rcp(c0); rcp runs parallel to the scan
            float fullA = dppm<0x141>(PA);
            float fullB = dppm<0x141>(PB);
            float cAc = fabsf(cA) < 1e-30f ? 1e-30f : cA;
            float cBc = fabsf(cB) < 1e-30f ? 1e-30f : cB;
            float outA = isq0 ? fullA * __builtin_amdgcn_rcpf(cAc) : PA;
            float outB = isq0 ? fullB * __builtin_amdgcn_rcpf(cBc) : PB;

            // ---- activations: all via tanh Pade ----
            float actA = fmaf(tanh_pade(outA * 0.5f), 0.5f, 0.5f);  // sigma (f,i)
            float actB = fmaf(tanh_pade(outB * sB), aB, bB);        // tanh(u)/sigma(o)

            // ---- R3: gather f,i,u,o for unit q ----
            float rA = dppm<0x128>(actA);
            float rB = dppm<0x128>(actB);
            float fv = lo8 ? actA : rA;
            float iv = lo8 ? rA : actA;
            float uv = lo8 ? actB : rB;
            float ov = lo8 ? rB : actB;

            // ---- state update ----
            float ncx = fmaf(fv, cx, iv * uv);
            float nhx = ov * tanh_pade(ncx);
            cx = ncx;
            hx = nhx;

            if (lo8) __builtin_nontemporal_store(nhx, outp + t * (BATCH * 8));
        }
    }

    if (lo8) {
        __builtin_nontemporal_store(hx, out + T_STEPS * BATCH * 8 + b * 8 + q);
        __builtin_nontemporal_store(cx, out + T_STEPS * BATCH * 8 + (BATCH + b) * 8 + q);
    }
}

// ---------------------------------------------------------------------------
extern "C" void kernel_launch(void* const* d_in, const int* in_sizes, int n_in,
                              void* d_out, int out_size, void* d_ws, size_t ws_size,
                              hipStream_t stream) {
    const float* inp = (const float*)d_in[0];
    const float* Wf  = (const float*)d_in[1];
    const float* bf  = (const float*)d_in[2];
    const float* Wi  = (const float*)d_in[3];
    const float* bi  = (const float*)d_in[4];
    const float* Wu  = (const float*)d_in[5];
    const float* bu  = (const float*)d_in[6];
    const float* Wo  = (const float*)d_in[7];
    const float* bo  = (const float*)d_in[8];
    const float* thf = (const float*)d_in[9];
    const float* thi = (const float*)d_in[10];
    const float* thu = (const float*)d_in[11];
    const float* tho = (const float*)d_in[12];

    float* X   = (float*)d_ws;              // (T*B, 32) fp32 = 33.5 MB
    float* out = (float*)d_out;

    qlstm_xproj<<<(T_STEPS * BATCH) / 64, 128, 0, stream>>>(
        inp, Wf, bf, Wi, bi, Wu, bu, Wo, bo, thf, thi, thu, tho, X);

    qlstm_rec<<<BATCH / 4, 64, 0, stream>>>(X, Wf, Wi, Wu, Wo, out);
}

// Round 4
// 174.183 us; speedup vs baseline: 1.3353x; 1.0262x over previous
//
#include <hip/hip_runtime.h>

#define T_STEPS 512
#define BATCH   512
#define IN_DIM  128
#define GDIM    32   // 4 gates x 8 qubits
#define PF_D    8    // prefetch depth (steps of X ahead in registers)
#define INV2PI  0.15915494309189535f

typedef float f4 __attribute__((ext_vector_type(4)));

// ---------------------------------------------------------------------------
// DPP helper: quad_perm bcast j: ctrl=j*0x55 ; row_shr:n = 0x110|n ;
// row_ror:8 = 0x128 ; row_half_mirror = 0x141 (mirror within 8-lane half-row).
// ---------------------------------------------------------------------------
template <int CTRL>
__device__ __forceinline__ float dppm(float x) {
    return __int_as_float(__builtin_amdgcn_mov_dpp(__float_as_int(x), CTRL, 0xF, 0xF, true));
}

// tanh Pade[5/4]: x(945+105u+u^2)/(945+420u+15u^2), u=x^2.
// err <= ~5e-5 on [-2.2,2.2] (|cx| <= 2.071 by contraction), ~1e-7 on [-1,1].
__device__ __forceinline__ float tanh_pade(float x) {
    float u = x * x;
    float n = fmaf(u, u + 105.0f, 945.0f);
    float d = fmaf(u, fmaf(u, 15.0f, 420.0f), 945.0f);
    return (x * n) * __builtin_amdgcn_rcpf(d);
}

// ---------------------------------------------------------------------------
// Kernel 1: X[row][g] = (inp[row] . W_gate[:,q] + b_gate[q] + theta_gate[q])/2pi
// 64 rows/block, 256 threads = 4 waves, wave w handles gate w (W stays on the
// wave-uniform s_load path). LDS 33KB -> 4 blocks/CU = 16 waves/CU: staging of
// some blocks overlaps compute of others. Input loads nontemporal (134MB
// streamed once) so X (33.5MB) stays L3-resident for the recurrence kernel.
// ---------------------------------------------------------------------------
__global__ __launch_bounds__(256) void qlstm_xproj(
    const float* __restrict__ inp,
    const float* __restrict__ Wf, const float* __restrict__ bf,
    const float* __restrict__ Wi, const float* __restrict__ bi,
    const float* __restrict__ Wu, const float* __restrict__ bu,
    const float* __restrict__ Wo, const float* __restrict__ bo,
    const float* __restrict__ thf, const float* __restrict__ thi,
    const float* __restrict__ thu, const float* __restrict__ tho,
    float* __restrict__ X)
{
    __shared__ float tile[64 * 129];
    const int tid = threadIdx.x;
    const long long row0 = (long long)blockIdx.x * 64;

    // stage 64 rows x 128 cols (32KB), coalesced float4, 8 per thread
    const f4* src = (const f4*)(inp + row0 * IN_DIM);
    #pragma unroll
    for (int i = 0; i < 8; ++i) {
        int f = tid + i * 256;            // 0..2047
        f4 v = __builtin_nontemporal_load(src + f);
        int r = f >> 5, c = (f & 31) << 2;
        float* d = &tile[r * 129 + c];
        d[0] = v.x; d[1] = v.y; d[2] = v.z; d[3] = v.w;
    }
    __syncthreads();

    const int g  = __builtin_amdgcn_readfirstlane(tid >> 6);  // wave id = gate
    const int rl = tid & 63;                                  // row within tile

    const float* W  = (g == 0) ? Wf : (g == 1) ? Wi : (g == 2) ? Wu : Wo;
    const float* B  = (g == 0) ? bf : (g == 1) ? bi : (g == 2) ? bu : bo;
    const float* TH = (g == 0) ? thf : (g == 1) ? thi : (g == 2) ? thu : tho;

    float acc[8];
    #pragma unroll
    for (int j = 0; j < 8; ++j) acc[j] = B[j] + TH[j];

    #pragma unroll 8
    for (int k = 0; k < IN_DIM; ++k) {
        float v = tile[rl * 129 + k];     // banks (rl+k)%32: 2-way = free
        #pragma unroll
        for (int j = 0; j < 8; ++j)
            acc[j] = fmaf(v, W[k * 8 + j], acc[j]);   // uniform -> s_load
    }

    float4* Xo = (float4*)(X + (row0 + rl) * GDIM + g * 8);
    Xo[0] = make_float4(acc[0] * INV2PI, acc[1] * INV2PI, acc[2] * INV2PI, acc[3] * INV2PI);
    Xo[1] = make_float4(acc[4] * INV2PI, acc[5] * INV2PI, acc[6] * INV2PI, acc[7] * INV2PI);
}

// ---------------------------------------------------------------------------
// Kernel 2: serial recurrence. ONE batch per wave (512 single-wave blocks,
// 2 waves/CU on distinct SIMDs): per-wave instruction stream is identical to
// the packed version (DPP is whole-wave), so this spreads the serial chain
// over 4x more SIMDs. Lanes 16-63 mirror lane group 0; only lanes 0-7 store.
// X pre-scaled by 1/2pi -> raw v_cos (cos(2pi x)) without the range mul.
// ---------------------------------------------------------------------------
__global__ __launch_bounds__(64) void qlstm_rec(
    const float* __restrict__ X,
    const float* __restrict__ Wf, const float* __restrict__ Wi,
    const float* __restrict__ Wu, const float* __restrict__ Wo,
    float* __restrict__ out)
{
    const int lane = threadIdx.x;
    const int l    = lane & 15;
    const int q    = lane & 7;
    const int gA   = (lane >> 3) & 1;
    const int b    = blockIdx.x;

    const bool ql   = ((lane >> 2) & 1) == 0;  // low quad of 8-group
    const bool lo8  = (l < 8);
    const bool st8  = (lane < 8);              // store group only
    const bool ge1  = (q >= 1), ge2 = (q >= 2), ge4 = (q >= 4);
    const bool isq0 = (q == 0);

    const float* WA = gA ? Wi : Wf;
    const float* WB = gA ? Wo : Wu;
    float wA[8], wB[8];
    #pragma unroll
    for (int k = 0; k < 8; ++k) {
        wA[k] = WA[(IN_DIM + k) * 8 + q] * INV2PI;   // match X pre-scale
        wB[k] = WB[(IN_DIM + k) * 8 + q] * INV2PI;
    }

    // B-stream activation fold: lo8 = u-gate (tanh), hi8 = o-gate (sigmoid)
    const float sB = lo8 ? 1.0f : 0.5f;
    const float aB = lo8 ? 1.0f : 0.5f;
    const float bB = lo8 ? 0.0f : 0.5f;

    float hx = 0.0f, cx = 0.0f;

    const int S = BATCH * GDIM;               // elements per time slice
    const float* bp = X + b * GDIM;

    // depth-8 rolling register prefetch queue (X is L3-resident)
    float qAv[PF_D], qBv[PF_D];
    #pragma unroll
    for (int d = 0; d < PF_D; ++d) {
        qAv[d] = bp[d * S + l];
        qBv[d] = bp[d * S + 16 + l];
    }

    float* outp = out + b * 8 + q;

    for (int tt = 0; tt < T_STEPS; tt += PF_D) {
        #pragma unroll
        for (int r = 0; r < PF_D; ++r) {
            const int t = tt + r;
            float xvA = qAv[r], xvB = qBv[r];
            int tp = t + PF_D; if (tp > T_STEPS - 1) tp = T_STEPS - 1;
            qAv[r] = bp[tp * S + l];
            qBv[r] = bp[tp * S + 16 + l];

            // ---- R1: broadcast hx[0..7] within 8-group ----
            float a0 = dppm<0x00>(hx), b0 = dppm<0x141>(a0);
            float a1 = dppm<0x55>(hx), b1 = dppm<0x141>(a1);
            float a2 = dppm<0xAA>(hx), b2 = dppm<0x141>(a2);
            float a3 = dppm<0xFF>(hx), b3 = dppm<0x141>(a3);
            float h0 = ql ? a0 : b0, h4 = ql ? b0 : a0;
            float h1 = ql ? a1 : b1, h5 = ql ? b1 : a1;
            float h2 = ql ? a2 : b2, h6 = ql ? b2 : a2;
            float h3 = ql ? a3 : b3, h7 = ql ? b3 : a3;

            float zA = xvA + (((h0 * wA[0] + h1 * wA[1]) + (h2 * wA[2] + h3 * wA[3]))
                            + ((h4 * wA[4] + h5 * wA[5]) + (h6 * wA[6] + h7 * wA[7])));
            float zB = xvB + (((h0 * wB[0] + h1 * wB[1]) + (h2 * wB[2] + h3 * wB[3]))
                            + ((h4 * wB[4] + h5 * wB[5]) + (h6 * wB[6] + h7 * wB[7])));

            float cA = __builtin_amdgcn_cosf(zA);   // cos(2pi*zA) = cos(z_raw)
            float cB = __builtin_amdgcn_cosf(zB);

            // ---- R2: masked DPP prefix-product scan within 8-group ----
            float PA = cA, PB = cB, tv;
            tv = dppm<0x111>(PA); PA *= (ge1 ? tv : 1.0f);
            tv = dppm<0x111>(PB); PB *= (ge1 ? tv : 1.0f);
            tv = dppm<0x112>(PA); PA *= (ge2 ? tv : 1.0f);
            tv = dppm<0x112>(PB); PB *= (ge2 ? tv : 1.0f);
            tv = dppm<0x114>(PA); PA *= (ge4 ? tv : 1.0f);
            tv = dppm<0x114>(PB); PB *= (ge4 ? tv : 1.0f);
            // lane0: out0 = (c0..c7) * rcp(c0); rcp runs parallel to the scan
            float fullA = dppm<0x141>(PA);
            float fullB = dppm<0x141>(PB);
            float cAc = fabsf(cA) < 1e-30f ? 1e-30f : cA;
            float cBc = fabsf(cB) < 1e-30f ? 1e-30f : cB;
            float outA = isq0 ? fullA * __builtin_amdgcn_rcpf(cAc) : PA;
            float outB = isq0 ? fullB * __builtin_amdgcn_rcpf(cBc) : PB;

            // ---- activations via shared tanh Pade ----
            float actA = fmaf(tanh_pade(outA * 0.5f), 0.5f, 0.5f);  // sigma (f,i)
            float actB = fmaf(tanh_pade(outB * sB), aB, bB);        // tanh(u)/sigma(o)

            // ---- R3: gather f,i,u,o for unit q ----
            float rA = dppm<0x128>(actA);
            float rB = dppm<0x128>(actB);
            float fv = lo8 ? actA : rA;
            float iv = lo8 ? rA : actA;
            float uv = lo8 ? actB : rB;
            float ov = lo8 ? rB : actB;

            // ---- state update ----
            float ncx = fmaf(fv, cx, iv * uv);
            float nhx = ov * tanh_pade(ncx);
            cx = ncx;
            hx = nhx;

            if (st8) __builtin_nontemporal_store(nhx, outp + t * (BATCH * 8));
        }
    }

    if (st8) {
        __builtin_nontemporal_store(hx, out + T_STEPS * BATCH * 8 + b * 8 + q);
        __builtin_nontemporal_store(cx, out + T_STEPS * BATCH * 8 + (BATCH + b) * 8 + q);
    }
}

// ---------------------------------------------------------------------------
extern "C" void kernel_launch(void* const* d_in, const int* in_sizes, int n_in,
                              void* d_out, int out_size, void* d_ws, size_t ws_size,
                              hipStream_t stream) {
    const float* inp = (const float*)d_in[0];
    const float* Wf  = (const float*)d_in[1];
    const float* bf  = (const float*)d_in[2];
    const float* Wi  = (const float*)d_in[3];
    const float* bi  = (const float*)d_in[4];
    const float* Wu  = (const float*)d_in[5];
    const float* bu  = (const float*)d_in[6];
    const float* Wo  = (const float*)d_in[7];
    const float* bo  = (const float*)d_in[8];
    const float* thf = (const float*)d_in[9];
    const float* thi = (const float*)d_in[10];
    const float* thu = (const float*)d_in[11];
    const float* tho = (const float*)d_in[12];

    float* X   = (float*)d_ws;              // (T*B, 32) fp32 = 33.5 MB
    float* out = (float*)d_out;

    qlstm_xproj<<<(T_STEPS * BATCH) / 64, 256, 0, stream>>>(
        inp, Wf, bf, Wi, bi, Wu, bu, Wo, bo, thf, thi, thu, tho, X);

    qlstm_rec<<<BATCH, 64, 0, stream>>>(X, Wf, Wi, Wu, Wo, out);
}